// Round 9
// baseline (157.853 us; speedup 1.0000x reference)
//
#include <hip/hip_runtime.h>
#include <hip/hip_bf16.h>
#include <math.h>

#define D      256
#define N2     8192
#define NHALF  4096
#define NBLK   1024
#define TILE   128
#define BK     32
#define NCH    8       // 256 / BK
#define LDW    36      // LDS row stride in bf16 (72 B = 18 words; rows advance 18 banks mod 32 -> ~2-way max)

typedef __bf16 bf16x8_t __attribute__((ext_vector_type(8)));
typedef __bf16 bf16x4_t __attribute__((ext_vector_type(4)));
typedef float  f32x4_t  __attribute__((ext_vector_type(4)));

// ---------------- kernel 1: fused normalize + positives + denom/ticket zero --------
__global__ __launch_bounds__(256) void prep_kernel(const float* __restrict__ a,
                                                   const float* __restrict__ b,
                                                   __bf16* __restrict__ zb,
                                                   float* __restrict__ g_pos,
                                                   float* __restrict__ g_denom,
                                                   unsigned* __restrict__ g_ticket) {
    const int tid = threadIdx.x;
    const int gt  = blockIdx.x * 256 + tid;
    if (gt < N2) g_denom[gt] = 0.0f;
    if (gt == 0) *g_ticket = 0u;

    const int w = blockIdx.x * 4 + (tid >> 6);  // pair row in [0, NHALF)
    const int l = tid & 63;
    float4 x = ((const float4*)(a + (size_t)w * D))[l];
    float4 y = ((const float4*)(b + (size_t)w * D))[l];
    float sxx = x.x * x.x + x.y * x.y + x.z * x.z + x.w * x.w;
    float syy = y.x * y.x + y.y * y.y + y.z * y.z + y.w * y.w;
    float sxy = x.x * y.x + x.y * y.y + x.z * y.z + x.w * y.w;
    #pragma unroll
    for (int off = 32; off; off >>= 1) {
        sxx += __shfl_xor(sxx, off, 64);
        syy += __shfl_xor(syy, off, 64);
        sxy += __shfl_xor(sxy, off, 64);
    }
    const float rx = 1.0f / fmaxf(sqrtf(sxx), 1e-8f);
    const float ry = 1.0f / fmaxf(sqrtf(syy), 1e-8f);

    bf16x4_t ox, oy;
    ox[0] = (__bf16)(x.x * rx); ox[1] = (__bf16)(x.y * rx);
    ox[2] = (__bf16)(x.z * rx); ox[3] = (__bf16)(x.w * rx);
    oy[0] = (__bf16)(y.x * ry); oy[1] = (__bf16)(y.y * ry);
    oy[2] = (__bf16)(y.z * ry); oy[3] = (__bf16)(y.w * ry);
    *(bf16x4_t*)(zb + (size_t)w * D + l * 4)           = ox;
    *(bf16x4_t*)(zb + (size_t)(w + NHALF) * D + l * 4) = oy;

    if (l == 0) {
        const float p = sxy * rx * ry;
        g_pos[w]         = p;
        g_pos[w + NHALF] = p;
    }
}

// ---------------- kernel 2: round-5 reg-staged sim at 4 blocks/CU + ticket fin -----
// Round-8 post-mortem: global_load_lds staging regressed (95us, all pipes idle) --
// with K=256 the 4-chunk pipeline is all fill, no steady state; the L2 latency lands
// on the vmcnt(0) barrier drain. Reverting to the VERIFIED round-5 reg-staged
// structure (66us). This round's single change: BK=32 + LDW=36 shrinks LDS to
// 36.9 KB -> 4 blocks/CU (vs 2), with (256,2) so the allocator stays uncapped
// (round-7's spill came from the (256,4) 128-reg cap; round 5 measured 88 VGPR).
// Desynced blocks overlap staging stalls with MFMA/exp across the CU's 16 waves.
// Tiles XCD-swizzled so same-XCD blocks share the A panel in their L2.
__global__ __launch_bounds__(256, 2) void sim_kernel(const __bf16* __restrict__ zb,
                                                     float* __restrict__ g_denom,
                                                     const float* __restrict__ g_pos,
                                                     unsigned* __restrict__ g_ticket,
                                                     float* __restrict__ out) {
    __shared__ __bf16 ldsA[2][TILE * LDW];
    __shared__ __bf16 ldsB[2][TILE * LDW];
    __shared__ float  sw[4];
    __shared__ bool   amLast;

    const int tid    = threadIdx.x;
    const int bx     = blockIdx.x;
    const int l      = tid & 63;
    const int lane15 = l & 15;
    const int quad   = l >> 4;
    const int w      = tid >> 6;
    const int wr     = (w >> 1) * 64;          // wave row offset in tile
    const int wc     = (w & 1) * 64;           // wave col offset in tile

    // staging map: thread t -> row = t>>1 (0..127), half h = t&1 (32 B), 2 x b128
    const int r    = tid >> 1;
    const int h    = tid & 1;
    const int wofs = r * LDW + h * 16;

    // bijective XCD swizzle: grid 1024 = 8 XCDs x 128; same-XCD blocks -> consecutive
    // tiles -> shared A-panel rows in that XCD's L2.
    const int swz = (bx & 7) * 128 + (bx >> 3);

    for (int tl = swz; tl < 64 * 64; tl += NBLK) {
        const int bi = tl >> 6;
        const int bj = tl & 63;
        const __bf16* zbA = zb + (size_t)(bi * TILE + r) * D + h * 16;
        const __bf16* zbB = zb + (size_t)(bj * TILE + r) * D + h * 16;

        bf16x8_t sa0, sa1, sb0, sb1;
        auto load_regs = [&](int c) {
            const int k0 = c * BK;
            sa0 = *(const bf16x8_t*)(zbA + k0);
            sa1 = *(const bf16x8_t*)(zbA + k0 + 8);
            sb0 = *(const bf16x8_t*)(zbB + k0);
            sb1 = *(const bf16x8_t*)(zbB + k0 + 8);
        };
        auto write_lds = [&](int buf) {
            *(bf16x8_t*)(&ldsA[buf][wofs])     = sa0;
            *(bf16x8_t*)(&ldsA[buf][wofs + 8]) = sa1;
            *(bf16x8_t*)(&ldsB[buf][wofs])     = sb0;
            *(bf16x8_t*)(&ldsB[buf][wofs + 8]) = sb1;
        };

        f32x4_t acc[4][4];
        #pragma unroll
        for (int mi = 0; mi < 4; ++mi)
            #pragma unroll
            for (int nj = 0; nj < 4; ++nj)
                acc[mi][nj] = (f32x4_t){0.f, 0.f, 0.f, 0.f};

        auto compute = [&](int buf) {
            bf16x8_t af[4], bff[4];
            #pragma unroll
            for (int mi = 0; mi < 4; ++mi)
                af[mi] = *(const bf16x8_t*)(&ldsA[buf][(wr + mi * 16 + lane15) * LDW + quad * 8]);
            #pragma unroll
            for (int nj = 0; nj < 4; ++nj)
                bff[nj] = *(const bf16x8_t*)(&ldsB[buf][(wc + nj * 16 + lane15) * LDW + quad * 8]);
            #pragma unroll
            for (int mi = 0; mi < 4; ++mi)
                #pragma unroll
                for (int nj = 0; nj < 4; ++nj)
                    acc[mi][nj] = __builtin_amdgcn_mfma_f32_16x16x32_bf16(bff[nj], af[mi], acc[mi][nj], 0, 0, 0);
        };

        // prologue (safe vs prev tile: its last compute read buf 1; writes here hit buf 0)
        load_regs(0);
        write_lds(0);
        __syncthreads();

        int cur = 0;
        #pragma unroll
        for (int c = 0; c < NCH; ++c) {
            if (c + 1 < NCH) load_regs(c + 1);
            compute(cur);
            if (c + 1 < NCH) {
                write_lds(cur ^ 1);
                __syncthreads();
                cur ^= 1;
            }
        }

        // epilogue: e = exp(sim/T) = exp2(acc * 2/ln2); zero self-diag; row sums
        // acc[mi][nj]: row = bi*128+wr+mi*16+lane15, col = bj*128+wc+nj*16+quad*4+t
        const bool dw = (bi == bj) && (wr == wc);
        float rs[4] = {0.f, 0.f, 0.f, 0.f};
        #pragma unroll
        for (int mi = 0; mi < 4; ++mi) {
            #pragma unroll
            for (int nj = 0; nj < 4; ++nj) {
                #pragma unroll
                for (int t = 0; t < 4; ++t) {
                    float e = exp2f(acc[mi][nj][t] * 2.8853900817779268f);
                    if (dw && mi == nj && (quad * 4 + t) == lane15) e = 0.0f;
                    rs[mi] += e;
                }
            }
        }
        #pragma unroll
        for (int mi = 0; mi < 4; ++mi) {
            rs[mi] += __shfl_xor(rs[mi], 16, 64);
            rs[mi] += __shfl_xor(rs[mi], 32, 64);
        }
        if (l < 16) {
            #pragma unroll
            for (int mi = 0; mi < 4; ++mi)
                atomicAdd(&g_denom[bi * TILE + wr + mi * 16 + l], rs[mi]);
        }
        __syncthreads();   // all waves past buf-1 reads before next tile's prologue
    }

    // ---------------- last-block fin (verified rounds 7-8) ----------------
    if (tid == 0) {
        __threadfence();
        unsigned t = __hip_atomic_fetch_add(g_ticket, 1u, __ATOMIC_ACQ_REL,
                                            __HIP_MEMORY_SCOPE_AGENT);
        amLast = (t == NBLK - 1);
    }
    __syncthreads();
    if (!amLast) return;

    float local = 0.0f;
    for (int k = tid; k < N2; k += 256) {
        float dn = __hip_atomic_load(&g_denom[k], __ATOMIC_RELAXED,
                                     __HIP_MEMORY_SCOPE_AGENT);
        local += logf(dn) - 2.0f * g_pos[k];
    }
    #pragma unroll
    for (int off = 32; off; off >>= 1) local += __shfl_xor(local, off, 64);
    if (l == 0) sw[tid >> 6] = local;
    __syncthreads();
    if (tid == 0) out[0] = (sw[0] + sw[1] + sw[2] + sw[3]) / (float)N2;
}

extern "C" void kernel_launch(void* const* d_in, const int* in_sizes, int n_in,
                              void* d_out, int out_size, void* d_ws, size_t ws_size,
                              hipStream_t stream) {
    const float* emb_i = (const float*)d_in[0];
    const float* emb_j = (const float*)d_in[1];

    __bf16*   zb       = (__bf16*)d_ws;                                 // 4 MB
    float*    g_denom  = (float*)((char*)d_ws + (size_t)N2 * D * 2);    // 8192 fp32
    float*    g_pos    = g_denom + N2;                                  // 8192 fp32
    unsigned* g_ticket = (unsigned*)(g_pos + N2);                       // 1 u32
    float*    out      = (float*)d_out;

    prep_kernel<<<NHALF / 4, 256, 0, stream>>>(emb_i, emb_j, zb, g_pos, g_denom, g_ticket);
    sim_kernel<<<NBLK, 256, 0, stream>>>(zb, g_denom, g_pos, g_ticket, out);
}